// Round 1
// baseline (416.638 us; speedup 1.0000x reference)
//
#include <hip/hip_runtime.h>

// Decoder: scores[b,m] = sum_e ( sum_d sbj[b,0,d] * W_r[rel[b]][d][e] ) * obj[b,m][e]
// B=1024, D=512, N_OBJ=64, EDGE_COUNT=200. All f32.

#define D      512
#define NOBJ   64

__global__ __launch_bounds__(256) void decoder_kernel(
    const float* __restrict__ sbj,   // [B, 1, D]
    const float* __restrict__ obj,   // [B, NOBJ, D]
    const int*   __restrict__ rel,   // [B]
    const float* __restrict__ Wr,    // [EDGE_COUNT, D, D]
    float*       __restrict__ out)   // [B, NOBJ]
{
    const int b = blockIdx.x;
    const int t = threadIdx.x;      // 0..255

    __shared__ float s_lds[D];
    __shared__ float v_lds[D];

    // ---- load subject vector to LDS (coalesced float2) ----
    {
        const float2 sv = reinterpret_cast<const float2*>(sbj + (size_t)b * D)[t];
        s_lds[2 * t]     = sv.x;
        s_lds[2 * t + 1] = sv.y;
    }
    __syncthreads();

    // ---- phase 1: v[e] = sum_d s[d] * W[d][e]; thread t owns e = 2t, 2t+1 ----
    const float2* __restrict__ W2 =
        reinterpret_cast<const float2*>(Wr + (size_t)rel[b] * D * D);

    float acc0 = 0.f, acc1 = 0.f;
    #pragma unroll 8
    for (int d = 0; d < D; ++d) {
        const float  sd = s_lds[d];           // LDS broadcast (free)
        const float2 w  = W2[d * (D / 2) + t]; // coalesced 8B/lane
        acc0 = fmaf(sd, w.x, acc0);
        acc1 = fmaf(sd, w.y, acc1);
    }
    v_lds[2 * t]     = acc0;
    v_lds[2 * t + 1] = acc1;
    __syncthreads();

    // ---- phase 2: scores[m] = dot(v, obj[b,m,:]) ----
    // 4 waves x 16 m's each; lane l keeps v[8l..8l+7] in registers.
    const int wave = t >> 6;   // 0..3
    const int lane = t & 63;   // 0..63

    float vreg[8];
    #pragma unroll
    for (int k = 0; k < 8; ++k) vreg[k] = v_lds[lane * 8 + k];

    const float* __restrict__ objb = obj + (size_t)b * NOBJ * D;

    #pragma unroll 4
    for (int j = 0; j < 16; ++j) {
        const int m = wave * 16 + j;
        const float4* __restrict__ o4 =
            reinterpret_cast<const float4*>(objb + (size_t)m * D);
        const float4 a = o4[lane * 2];       // coalesced 16B/lane
        const float4 c = o4[lane * 2 + 1];

        float p = vreg[0] * a.x + vreg[1] * a.y + vreg[2] * a.z + vreg[3] * a.w
                + vreg[4] * c.x + vreg[5] * c.y + vreg[6] * c.z + vreg[7] * c.w;

        // 64-lane butterfly reduce
        #pragma unroll
        for (int off = 32; off > 0; off >>= 1)
            p += __shfl_down(p, off, 64);

        if (lane == 0) out[(size_t)b * NOBJ + m] = p;
    }
}

extern "C" void kernel_launch(void* const* d_in, const int* in_sizes, int n_in,
                              void* d_out, int out_size, void* d_ws, size_t ws_size,
                              hipStream_t stream) {
    const float* sbj = (const float*)d_in[0];   // [B,1,512]
    const float* obj = (const float*)d_in[1];   // [B,64,512]
    const int*   rel = (const int*)d_in[2];     // [B]
    const float* Wr  = (const float*)d_in[3];   // [200,512,512]
    float*       out = (float*)d_out;           // [B,64]

    const int B = in_sizes[2];                  // 1024
    decoder_kernel<<<dim3(B), dim3(256), 0, stream>>>(sbj, obj, rel, Wr, out);
}

// Round 2
// 382.802 us; speedup vs baseline: 1.0884x; 1.0884x over previous
//
#include <hip/hip_runtime.h>

// Decoder: scores[b,m] = sum_e ( sum_d sbj[b,0,d] * W_r[rel[b]][d][e] ) * obj[b,m][e]
// B=1024, D=512, N_OBJ=64, EDGE_COUNT=200. All f32.
//
// Strategy: sort batches by relation on-device, process up to G=8 batches that
// share a relation per block so each W_r matrix is fetched ~once (215 MB vs
// 1 GB logical), wide float4 W loads for latency hiding, then a separate
// obj-streaming score kernel.

#define D        512
#define NOBJ     64
#define EDGES    200
#define G        8       // batches per chunk

__device__ __forceinline__ float4 f4zero() { float4 z; z.x=z.y=z.z=z.w=0.f; return z; }

// ---------------- K0: bucket sort by relation + chunk table ----------------
__global__ __launch_bounds__(256) void prep_kernel(
    const int* __restrict__ rel, int B,
    int* __restrict__ sorted, int* __restrict__ chunk_rel,
    int* __restrict__ chunk_start, int* __restrict__ chunk_cnt,
    int* __restrict__ nchunks)
{
    __shared__ int cnt[EDGES];
    __shared__ int off[EDGES];
    __shared__ int pos[EDGES];
    __shared__ int nch;
    const int t = threadIdx.x;

    if (t < EDGES) cnt[t] = 0;
    if (t == 0) nch = 0;
    __syncthreads();

    for (int b = t; b < B; b += 256) atomicAdd(&cnt[rel[b]], 1);
    __syncthreads();

    if (t == 0) {                     // serial prefix over 200 — trivial
        int a = 0;
        for (int r = 0; r < EDGES; ++r) { off[r] = a; a += cnt[r]; }
    }
    if (t < EDGES) pos[t] = 0;
    __syncthreads();

    for (int b = t; b < B; b += 256) {
        const int r = rel[b];
        const int p = atomicAdd(&pos[r], 1);
        sorted[off[r] + p] = b;
    }

    if (t < EDGES) {
        const int n = cnt[t];
        if (n > 0) {
            const int nc   = (n + G - 1) / G;
            const int base = atomicAdd(&nch, nc);
            for (int k = 0; k < nc; ++k) {
                chunk_rel[base + k]   = t;
                chunk_start[base + k] = off[t] + k * G;
                chunk_cnt[base + k]   = min(G, n - k * G);
            }
        }
    }
    __syncthreads();
    if (t == 0) *nchunks = nch;
}

// ---------------- K1: grouped GEMV  V[b] = sbj[b] @ W_r ----------------
// Grid: 2 * MAXCHUNKS blocks; block = (chunk, column-half of 256 cols).
// Thread t: wave wv=t>>6 covers row d4+wv, lane covers 4 cols via float4.
__global__ __launch_bounds__(256) void gemv_kernel(
    const float* __restrict__ sbj, const float* __restrict__ Wr,
    const int* __restrict__ sorted,
    const int* __restrict__ chunk_rel, const int* __restrict__ chunk_start,
    const int* __restrict__ chunk_cnt, const int* __restrict__ nchunks,
    float* __restrict__ V)
{
    const int cid = blockIdx.x >> 1;
    if (cid >= *nchunks) return;
    const int colbase = (blockIdx.x & 1) * 256;
    const int t    = threadIdx.x;
    const int lane = t & 63;
    const int wv   = t >> 6;

    __shared__ float lds[8192];  // 32 KB: [0,4096) = s[8][512]; later reused as red[32][256]

    const int relid = chunk_rel[cid];
    const int start = chunk_start[cid];
    const int cnt   = chunk_cnt[cid];

    // load up to 8 subject vectors into LDS (zero-pad the rest)
    #pragma unroll
    for (int g = 0; g < G; ++g) {
        float2 v2;
        if (g < cnt) {
            v2 = reinterpret_cast<const float2*>(sbj + (size_t)sorted[start + g] * D)[t];
        } else { v2.x = 0.f; v2.y = 0.f; }
        lds[g * D + 2 * t]     = v2.x;
        lds[g * D + 2 * t + 1] = v2.y;
    }
    __syncthreads();

    // W[r][d][c]: float4 at relid*65536 + d*128 + colbase/4 + lane
    const float4* __restrict__ W4 =
        reinterpret_cast<const float4*>(Wr) + (size_t)relid * (D * D / 4) + (colbase >> 2) + lane;

    float4 acc[G];
    #pragma unroll
    for (int g = 0; g < G; ++g) acc[g] = f4zero();

    #pragma unroll 4
    for (int d4 = 0; d4 < D; d4 += 4) {
        const int d = d4 + wv;
        const float4 w = W4[(size_t)d * (D / 4)];   // 16B/lane, 1KB/wave, coalesced
        #pragma unroll
        for (int g = 0; g < G; ++g) {
            const float sg = lds[g * D + d];        // wave-uniform LDS broadcast
            acc[g].x = fmaf(sg, w.x, acc[g].x);
            acc[g].y = fmaf(sg, w.y, acc[g].y);
            acc[g].z = fmaf(sg, w.z, acc[g].z);
            acc[g].w = fmaf(sg, w.w, acc[g].w);
        }
    }
    __syncthreads();   // all s reads done; reuse lds as reduction buffer

    // red[(wv*8+g)][cidx], cidx = lane*4+j — contiguous float4 per lane, conflict-free
    #pragma unroll
    for (int g = 0; g < G; ++g)
        reinterpret_cast<float4*>(lds)[(wv * G + g) * 64 + lane] = acc[g];
    __syncthreads();

    // thread t owns column cidx = t: sum 4 row-parity partials, write V
    for (int g = 0; g < cnt; ++g) {
        const float s = lds[(0 * G + g) * 256 + t] + lds[(1 * G + g) * 256 + t]
                      + lds[(2 * G + g) * 256 + t] + lds[(3 * G + g) * 256 + t];
        V[(size_t)sorted[start + g] * D + colbase + t] = s;   // 1KB coalesced store
    }
}

// ---------------- K2: scores[b,m] = dot(V[b], obj[b,m]) ----------------
__global__ __launch_bounds__(256) void score_kernel(
    const float* __restrict__ V, const float* __restrict__ obj,
    float* __restrict__ out)
{
    const int b    = blockIdx.x;
    const int t    = threadIdx.x;
    const int lane = t & 63;
    const int wv   = t >> 6;

    const float4* __restrict__ v4 = reinterpret_cast<const float4*>(V + (size_t)b * D);
    const float4 a = v4[lane * 2];
    const float4 c = v4[lane * 2 + 1];
    float vreg[8] = {a.x, a.y, a.z, a.w, c.x, c.y, c.z, c.w};

    const float* __restrict__ objb = obj + (size_t)b * NOBJ * D;

    #pragma unroll 4
    for (int j = 0; j < 16; ++j) {
        const int m = wv * 16 + j;
        const float4* __restrict__ o4 = reinterpret_cast<const float4*>(objb + (size_t)m * D);
        const float4 x = o4[lane * 2];
        const float4 y = o4[lane * 2 + 1];

        float p = vreg[0] * x.x + vreg[1] * x.y + vreg[2] * x.z + vreg[3] * x.w
                + vreg[4] * y.x + vreg[5] * y.y + vreg[6] * y.z + vreg[7] * y.w;

        #pragma unroll
        for (int off = 32; off > 0; off >>= 1)
            p += __shfl_down(p, off, 64);

        if (lane == 0) out[(size_t)b * NOBJ + m] = p;
    }
}

// ---------------- fallback: round-1 fused kernel (if ws too small) ----------------
__global__ __launch_bounds__(256) void fused_kernel(
    const float* __restrict__ sbj, const float* __restrict__ obj,
    const int* __restrict__ rel, const float* __restrict__ Wr,
    float* __restrict__ out)
{
    const int b = blockIdx.x;
    const int t = threadIdx.x;
    __shared__ float s_lds[D];
    __shared__ float v_lds[D];
    {
        const float2 sv = reinterpret_cast<const float2*>(sbj + (size_t)b * D)[t];
        s_lds[2 * t] = sv.x; s_lds[2 * t + 1] = sv.y;
    }
    __syncthreads();
    const float2* __restrict__ W2 = reinterpret_cast<const float2*>(Wr + (size_t)rel[b] * D * D);
    float acc0 = 0.f, acc1 = 0.f;
    #pragma unroll 8
    for (int d = 0; d < D; ++d) {
        const float sd = s_lds[d];
        const float2 w = W2[d * (D / 2) + t];
        acc0 = fmaf(sd, w.x, acc0); acc1 = fmaf(sd, w.y, acc1);
    }
    v_lds[2 * t] = acc0; v_lds[2 * t + 1] = acc1;
    __syncthreads();
    const int wave = t >> 6, lane = t & 63;
    float vreg[8];
    #pragma unroll
    for (int k = 0; k < 8; ++k) vreg[k] = v_lds[lane * 8 + k];
    const float* __restrict__ objb = obj + (size_t)b * NOBJ * D;
    #pragma unroll 4
    for (int j = 0; j < 16; ++j) {
        const int m = wave * 16 + j;
        const float4* __restrict__ o4 = reinterpret_cast<const float4*>(objb + (size_t)m * D);
        const float4 a = o4[lane * 2];
        const float4 c = o4[lane * 2 + 1];
        float p = vreg[0]*a.x + vreg[1]*a.y + vreg[2]*a.z + vreg[3]*a.w
                + vreg[4]*c.x + vreg[5]*c.y + vreg[6]*c.z + vreg[7]*c.w;
        #pragma unroll
        for (int off = 32; off > 0; off >>= 1) p += __shfl_down(p, off, 64);
        if (lane == 0) out[(size_t)b * NOBJ + m] = p;
    }
}

extern "C" void kernel_launch(void* const* d_in, const int* in_sizes, int n_in,
                              void* d_out, int out_size, void* d_ws, size_t ws_size,
                              hipStream_t stream) {
    const float* sbj = (const float*)d_in[0];   // [B,1,512]
    const float* obj = (const float*)d_in[1];   // [B,64,512]
    const int*   rel = (const int*)d_in[2];     // [B]
    const float* Wr  = (const float*)d_in[3];   // [200,512,512]
    float*       out = (float*)d_out;           // [B,64]
    const int B = in_sizes[2];

    const int maxch = B / G + EDGES;            // Σ ceil(n_r/G) bound

    // workspace layout
    const size_t offV      = 0;
    const size_t offSorted = (size_t)B * D * 4;
    const size_t offCRel   = offSorted + (size_t)B * 4;
    const size_t offCStart = offCRel   + (size_t)maxch * 4;
    const size_t offCCnt   = offCStart + (size_t)maxch * 4;
    const size_t offNCh    = offCCnt   + (size_t)maxch * 4;
    const size_t needed    = offNCh + 64;

    if (ws_size < needed) {
        fused_kernel<<<dim3(B), dim3(256), 0, stream>>>(sbj, obj, rel, Wr, out);
        return;
    }

    char* ws = (char*)d_ws;
    float* V          = (float*)(ws + offV);
    int*   sorted     = (int*)(ws + offSorted);
    int*   chunk_rel  = (int*)(ws + offCRel);
    int*   chunk_start= (int*)(ws + offCStart);
    int*   chunk_cnt  = (int*)(ws + offCCnt);
    int*   nchunks    = (int*)(ws + offNCh);

    prep_kernel<<<dim3(1), dim3(256), 0, stream>>>(rel, B, sorted, chunk_rel,
                                                   chunk_start, chunk_cnt, nchunks);
    gemv_kernel<<<dim3(2 * maxch), dim3(256), 0, stream>>>(sbj, Wr, sorted,
                                                           chunk_rel, chunk_start,
                                                           chunk_cnt, nchunks, V);
    score_kernel<<<dim3(B), dim3(256), 0, stream>>>(V, obj, out);
}

// Round 3
// 375.135 us; speedup vs baseline: 1.1106x; 1.0204x over previous
//
#include <hip/hip_runtime.h>

// Decoder: scores[b,m] = sum_e ( sum_d sbj[b,0,d] * W_r[rel[b]][d][e] ) * obj[b,m][e]
// B=1024, D=512, N_OBJ=64, EDGE_COUNT=200. All f32.
//
// Pipeline: K0 bucket-sort batches by relation (chunks of <=8 sharing one W_r),
// K1 grouped GEMV with 4-way column split (W fetched ~once: ~210 MB),
// K2 obj-streaming scores. Memory-bound; floor ~55us of HBM traffic.

#define D        512
#define NOBJ     64
#define EDGES    200
#define G        8       // batches per chunk
#define CSPL     4       // column splits (128 cols per block)

__device__ __forceinline__ float4 f4zero() { float4 z; z.x=z.y=z.z=z.w=0.f; return z; }

// ---------------- K0: bucket sort by relation + chunk table ----------------
__global__ __launch_bounds__(256) void prep_kernel(
    const int* __restrict__ rel, int B,
    int* __restrict__ sorted, int* __restrict__ chunk_rel,
    int* __restrict__ chunk_start, int* __restrict__ chunk_cnt,
    int* __restrict__ nchunks)
{
    __shared__ int cnt[EDGES];
    __shared__ int off[EDGES];
    __shared__ int pos[EDGES];
    __shared__ int nch;
    const int t = threadIdx.x;

    if (t < EDGES) cnt[t] = 0;
    if (t == 0) nch = 0;
    __syncthreads();

    for (int b = t; b < B; b += 256) atomicAdd(&cnt[rel[b]], 1);
    __syncthreads();

    if (t == 0) {                     // serial prefix over 200 — trivial
        int a = 0;
        for (int r = 0; r < EDGES; ++r) { off[r] = a; a += cnt[r]; }
    }
    if (t < EDGES) pos[t] = 0;
    __syncthreads();

    for (int b = t; b < B; b += 256) {
        const int r = rel[b];
        const int p = atomicAdd(&pos[r], 1);
        sorted[off[r] + p] = b;
    }

    if (t < EDGES) {
        const int n = cnt[t];
        if (n > 0) {
            const int nc   = (n + G - 1) / G;
            const int base = atomicAdd(&nch, nc);
            for (int k = 0; k < nc; ++k) {
                chunk_rel[base + k]   = t;
                chunk_start[base + k] = off[t] + k * G;
                chunk_cnt[base + k]   = min(G, n - k * G);
            }
        }
    }
    __syncthreads();
    if (t == 0) *nchunks = nch;
}

// ---------------- K1: grouped GEMV  V[b] = sbj[b] @ W_r ----------------
// Block = (chunk, 128-col slice). 256 threads = 8 row-groups x 32 float4 lanes.
// unroll 8 -> 128 B/thread in flight on the W stream.
__global__ __launch_bounds__(256) void gemv_kernel(
    const float* __restrict__ sbj, const float* __restrict__ Wr,
    const int* __restrict__ sorted,
    const int* __restrict__ chunk_rel, const int* __restrict__ chunk_start,
    const int* __restrict__ chunk_cnt, const int* __restrict__ nchunks,
    float* __restrict__ V)
{
    const int cid = blockIdx.x >> 2;
    if (cid >= *nchunks) return;
    const int colbase = (blockIdx.x & 3) * 128;
    const int t    = threadIdx.x;
    const int lane = t & 31;      // float4 lane -> 4 cols
    const int rg   = t >> 5;      // row group 0..7

    __shared__ float lds[8192];   // 32 KB: s[8][512] in [0,4096); partials use all 8192

    const int relid = chunk_rel[cid];
    const int start = chunk_start[cid];
    const int cnt   = chunk_cnt[cid];

    // load up to 8 subject vectors into LDS (zero-pad the rest)
    #pragma unroll
    for (int g = 0; g < G; ++g) {
        float2 v2; v2.x = 0.f; v2.y = 0.f;
        if (g < cnt)
            v2 = reinterpret_cast<const float2*>(sbj + (size_t)sorted[start + g] * D)[t];
        lds[g * D + 2 * t]     = v2.x;
        lds[g * D + 2 * t + 1] = v2.y;
    }
    __syncthreads();

    const float4* __restrict__ W4 =
        reinterpret_cast<const float4*>(Wr) + (size_t)relid * (D * D / 4) + (colbase >> 2) + lane;

    float4 acc[G];
    #pragma unroll
    for (int g = 0; g < G; ++g) acc[g] = f4zero();

    #pragma unroll 8
    for (int d8 = 0; d8 < D; d8 += 8) {
        const int row = d8 + rg;
        const float4 w = W4[(size_t)row * (D / 4)];   // 16B/lane
        #pragma unroll
        for (int g = 0; g < G; ++g) {
            const float sg = lds[g * D + row];        // 2-addr broadcast per wave (free)
            acc[g].x = fmaf(sg, w.x, acc[g].x);
            acc[g].y = fmaf(sg, w.y, acc[g].y);
            acc[g].z = fmaf(sg, w.z, acc[g].z);
            acc[g].w = fmaf(sg, w.w, acc[g].w);
        }
    }
    __syncthreads();   // subjects fully consumed; reuse LDS for partials

    // partial[rg][g][lane] as float4 at index (rg*8+g)*32 + lane
    #pragma unroll
    for (int g = 0; g < G; ++g)
        reinterpret_cast<float4*>(lds)[(rg * G + g) * 32 + lane] = acc[g];
    __syncthreads();

    // reduce 8 row-groups: thread t -> col = t&127, handles g = (t>>7)*4 + gi
    const int col = t & 127;
    const int gg  = t >> 7;
    #pragma unroll
    for (int gi = 0; gi < 4; ++gi) {
        const int g = gg * 4 + gi;
        if (g < cnt) {
            float s = 0.f;
            #pragma unroll
            for (int r = 0; r < 8; ++r) s += lds[(r * G + g) * 128 + col];
            V[(size_t)sorted[start + g] * D + colbase + col] = s;
        }
    }
}

// ---------------- K2: scores[b,m] = dot(V[b], obj[b,m]) ----------------
__global__ __launch_bounds__(256) void score_kernel(
    const float* __restrict__ V, const float* __restrict__ obj,
    float* __restrict__ out)
{
    const int b    = blockIdx.x;
    const int t    = threadIdx.x;
    const int lane = t & 63;
    const int wv   = t >> 6;

    const float4* __restrict__ v4 = reinterpret_cast<const float4*>(V + (size_t)b * D);
    const float4 a = v4[lane * 2];
    const float4 c = v4[lane * 2 + 1];
    float vreg[8] = {a.x, a.y, a.z, a.w, c.x, c.y, c.z, c.w};

    const float* __restrict__ objb = obj + (size_t)b * NOBJ * D;

    #pragma unroll 4
    for (int j = 0; j < 16; ++j) {
        const int m = wv * 16 + j;
        const float4* __restrict__ o4 = reinterpret_cast<const float4*>(objb + (size_t)m * D);
        const float4 x = o4[lane * 2];
        const float4 y = o4[lane * 2 + 1];

        float p = vreg[0] * x.x + vreg[1] * x.y + vreg[2] * x.z + vreg[3] * x.w
                + vreg[4] * y.x + vreg[5] * y.y + vreg[6] * y.z + vreg[7] * y.w;

        #pragma unroll
        for (int off = 32; off > 0; off >>= 1)
            p += __shfl_down(p, off, 64);

        if (lane == 0) out[(size_t)b * NOBJ + m] = p;
    }
}

// ---------------- fallback: fused kernel (if ws too small) ----------------
__global__ __launch_bounds__(256) void fused_kernel(
    const float* __restrict__ sbj, const float* __restrict__ obj,
    const int* __restrict__ rel, const float* __restrict__ Wr,
    float* __restrict__ out)
{
    const int b = blockIdx.x;
    const int t = threadIdx.x;
    __shared__ float s_lds[D];
    __shared__ float v_lds[D];
    {
        const float2 sv = reinterpret_cast<const float2*>(sbj + (size_t)b * D)[t];
        s_lds[2 * t] = sv.x; s_lds[2 * t + 1] = sv.y;
    }
    __syncthreads();
    const float2* __restrict__ W2 = reinterpret_cast<const float2*>(Wr + (size_t)rel[b] * D * D);
    float acc0 = 0.f, acc1 = 0.f;
    #pragma unroll 8
    for (int d = 0; d < D; ++d) {
        const float sd = s_lds[d];
        const float2 w = W2[d * (D / 2) + t];
        acc0 = fmaf(sd, w.x, acc0); acc1 = fmaf(sd, w.y, acc1);
    }
    v_lds[2 * t] = acc0; v_lds[2 * t + 1] = acc1;
    __syncthreads();
    const int wave = t >> 6, lane = t & 63;
    float vreg[8];
    #pragma unroll
    for (int k = 0; k < 8; ++k) vreg[k] = v_lds[lane * 8 + k];
    const float* __restrict__ objb = obj + (size_t)b * NOBJ * D;
    #pragma unroll 4
    for (int j = 0; j < 16; ++j) {
        const int m = wave * 16 + j;
        const float4* __restrict__ o4 = reinterpret_cast<const float4*>(objb + (size_t)m * D);
        const float4 a = o4[lane * 2];
        const float4 c = o4[lane * 2 + 1];
        float p = vreg[0]*a.x + vreg[1]*a.y + vreg[2]*a.z + vreg[3]*a.w
                + vreg[4]*c.x + vreg[5]*c.y + vreg[6]*c.z + vreg[7]*c.w;
        #pragma unroll
        for (int off = 32; off > 0; off >>= 1) p += __shfl_down(p, off, 64);
        if (lane == 0) out[(size_t)b * NOBJ + m] = p;
    }
}

extern "C" void kernel_launch(void* const* d_in, const int* in_sizes, int n_in,
                              void* d_out, int out_size, void* d_ws, size_t ws_size,
                              hipStream_t stream) {
    const float* sbj = (const float*)d_in[0];   // [B,1,512]
    const float* obj = (const float*)d_in[1];   // [B,64,512]
    const int*   rel = (const int*)d_in[2];     // [B]
    const float* Wr  = (const float*)d_in[3];   // [200,512,512]
    float*       out = (float*)d_out;           // [B,64]
    const int B = in_sizes[2];

    const int maxch = B / G + EDGES;            // bound on sum ceil(n_r/G)

    // workspace layout
    const size_t offV      = 0;
    const size_t offSorted = (size_t)B * D * 4;
    const size_t offCRel   = offSorted + (size_t)B * 4;
    const size_t offCStart = offCRel   + (size_t)maxch * 4;
    const size_t offCCnt   = offCStart + (size_t)maxch * 4;
    const size_t offNCh    = offCCnt   + (size_t)maxch * 4;
    const size_t needed    = offNCh + 64;

    if (ws_size < needed) {
        fused_kernel<<<dim3(B), dim3(256), 0, stream>>>(sbj, obj, rel, Wr, out);
        return;
    }

    char* ws = (char*)d_ws;
    float* V           = (float*)(ws + offV);
    int*   sorted      = (int*)(ws + offSorted);
    int*   chunk_rel   = (int*)(ws + offCRel);
    int*   chunk_start = (int*)(ws + offCStart);
    int*   chunk_cnt   = (int*)(ws + offCCnt);
    int*   nchunks     = (int*)(ws + offNCh);

    prep_kernel<<<dim3(1), dim3(256), 0, stream>>>(rel, B, sorted, chunk_rel,
                                                   chunk_start, chunk_cnt, nchunks);
    gemv_kernel<<<dim3(CSPL * maxch), dim3(256), 0, stream>>>(sbj, Wr, sorted,
                                                              chunk_rel, chunk_start,
                                                              chunk_cnt, nchunks, V);
    score_kernel<<<dim3(B), dim3(256), 0, stream>>>(V, obj, out);
}